// Round 14
// baseline (292.473 us; speedup 1.0000x reference)
//
#include <hip/hip_runtime.h>
#include <hip/hip_fp16.h>
#include <hip/hip_cooperative_groups.h>

namespace cg = cooperative_groups;

static inline int cdiv(int a, int b) { return (a + b - 1) / b; }

#define NWORD 25600   // 102400 B LDS = byte counters for N <= 102400
#define HC    64      // edge chunks (= hist blocks)
#define NBLK  256     // cooperative sort blocks (<= CU count)
#define CTHR  1024
#define MAXK  7       // edges per thread: NBLK*CTHR*MAXK >= E  (1.835M >= 1.6M)
#define BKT_SHIFT 12
#define BKT   (1 << BKT_SHIFT)

struct h2x4 { __half2 a, b, c, d; };  // 16 B = 8 halves

// ---------------- phase A: single-pass full-range LDS histogram + rank ----------------
__global__ __launch_bounds__(1024) void k_hist(const int* __restrict__ dst, int E, int N, int chunk,
                                               unsigned char* __restrict__ rank8,
                                               unsigned char* __restrict__ Mb) {
    __shared__ unsigned int cnt[NWORD];
    int c = blockIdx.x;
    for (int i = threadIdx.x; i < NWORD; i += 1024) cnt[i] = 0;
    __syncthreads();
    int ebeg = c * chunk;
    int eend = min(E, ebeg + chunk);
    for (int e = ebeg + threadIdx.x; e < eend; e += 1024) {
        int d = dst[e];
        int sh = (d & 3) * 8;
        unsigned int old = atomicAdd(&cnt[d >> 2], 1u << sh);  // LDS atomic
        rank8[e] = (unsigned char)((old >> sh) & 0xFF);
    }
    __syncthreads();
    unsigned int* Mrow = (unsigned int*)(Mb + (size_t)c * N);
    int nw = N >> 2;
    for (int i = threadIdx.x; i < nw; i += 1024) Mrow[i] = cnt[i];
}

// ---------------- deg + dinv + per-(chunk,node) byte prefix (fused) ----------------
__global__ __launch_bounds__(256) void k_degpre(const unsigned char* __restrict__ Mb, int N,
                                                unsigned char* __restrict__ pre8,
                                                int* __restrict__ deg, float* __restrict__ dinv) {
    int i = blockIdx.x * 256 + threadIdx.x;  // group of 4 nodes
    if (i >= (N >> 2)) return;
    unsigned int s0 = 0, s1 = 0, s2 = 0, s3 = 0;
#pragma unroll
    for (int c = 0; c < HC; ++c) {
        unsigned int w = *(const unsigned int*)(Mb + (size_t)c * N + 4 * i);
        *(unsigned int*)(pre8 + (size_t)c * N + 4 * i) = s0 | (s1 << 8) | (s2 << 16) | (s3 << 24);
        s0 += w & 0xFF; s1 += (w >> 8) & 0xFF; s2 += (w >> 16) & 0xFF; s3 += (w >> 24) & 0xFF;
    }
    ((int4*)deg)[i] = make_int4((int)s0, (int)s1, (int)s2, (int)s3);
    ((float4*)dinv)[i] = make_float4(rsqrtf((float)(s0 + 1)), rsqrtf((float)(s1 + 1)),
                                     rsqrtf((float)(s2 + 1)), rsqrtf((float)(s3 + 1)));
}

// ---------------- exclusive scan for node offsets (hierarchical) ----------------
#define SCAN_BS 1024

__global__ __launch_bounds__(SCAN_BS) void k_blocksum(const int* __restrict__ deg, int N, int* __restrict__ bsum) {
    __shared__ int s[SCAN_BS];
    int t = threadIdx.x;
    int i = blockIdx.x * SCAN_BS + t;
    s[t] = (i < N) ? deg[i] : 0;
    __syncthreads();
    for (int off = SCAN_BS / 2; off > 0; off >>= 1) {
        if (t < off) s[t] += s[t + off];
        __syncthreads();
    }
    if (t == 0) bsum[blockIdx.x] = s[0];
}

__global__ __launch_bounds__(128) void k_scan_bsums(const int* __restrict__ bsum, int NB, int* __restrict__ boff) {
    __shared__ int s[128];
    int t = threadIdx.x;
    int v = (t < NB) ? bsum[t] : 0;
    s[t] = v;
    __syncthreads();
    for (int off = 1; off < 128; off <<= 1) {
        int u = (t >= off) ? s[t - off] : 0;
        __syncthreads();
        s[t] += u;
        __syncthreads();
    }
    if (t < NB) boff[t] = s[t] - v;  // exclusive
}

__global__ __launch_bounds__(SCAN_BS) void k_scan_final(const int* __restrict__ deg, int N,
                                                        const int* __restrict__ boff,
                                                        int* __restrict__ offsets, int E) {
    __shared__ int s[SCAN_BS];
    int t = threadIdx.x;
    int i = blockIdx.x * SCAN_BS + t;
    int v = (i < N) ? deg[i] : 0;
    s[t] = v;
    __syncthreads();
    for (int off = 1; off < SCAN_BS; off <<= 1) {
        int u = (t >= off) ? s[t - off] : 0;
        __syncthreads();
        s[t] += u;
        __syncthreads();
    }
    if (i < N) offsets[i] = boff[blockIdx.x] + s[t] - v;
    if (blockIdx.x == 0 && t == 0) offsets[N] = E;
}

// ---------------- cooperative fused bucket sort: pos -> dense packed pairs ----------------
// phase1: per-edge pos in regs + LDS bucket hist; scan (grid-wide); phase2: dense pair write.
__global__ __launch_bounds__(CTHR) void k_sortcsr(const int* __restrict__ ei, int E, int N, int chunk,
                                                  int epb, int nbuk, int clen,
                                                  const int* __restrict__ offsets,
                                                  const unsigned char* __restrict__ pre8,
                                                  const unsigned char* __restrict__ rank8,
                                                  int* __restrict__ cnt, int* __restrict__ bsum2,
                                                  int* __restrict__ boff2, int* __restrict__ cbase,
                                                  unsigned int* __restrict__ pairs) {
    cg::grid_group grid = cg::this_grid();
    __shared__ int h[512];
    __shared__ int s[CTHR];
    int blk = blockIdx.x, tid = threadIdx.x;
    for (int b = tid; b < nbuk; b += CTHR) h[b] = 0;
    __syncthreads();
    int beg = blk * epb;
    int end = min(E, beg + epb);
    const int* dst = ei + E;
    int c0 = beg / chunk;                 // epb <= chunk: block spans <= 2 chunks
    int bound = (c0 + 1) * chunk;
    int ps[MAXK], sr[MAXK];
#pragma unroll
    for (int k = 0; k < MAXK; ++k) {
        int e = beg + tid + k * CTHR;
        ps[k] = -1;
        if (e < end) {
            int d = dst[e];
            int c = (e < bound) ? c0 : c0 + 1;
            int pos = offsets[d] + (int)pre8[(size_t)c * N + d] + (int)rank8[e];
            ps[k] = pos;
            sr[k] = ei[e];
            atomicAdd(&h[pos >> BKT_SHIFT], 1);
        }
    }
    __syncthreads();
    for (int b = tid; b < nbuk; b += CTHR) cnt[b * NBLK + blk] = h[b];
    grid.sync();
    // ---- scan cnt[0..clen) ----
    int NB2 = (clen + CTHR - 1) / CTHR;
    if (blk < NB2) {  // step A: block sums
        int i = blk * CTHR + tid;
        s[tid] = (i < clen) ? cnt[i] : 0;
        __syncthreads();
        for (int off = CTHR / 2; off > 0; off >>= 1) {
            if (tid < off) s[tid] += s[tid + off];
            __syncthreads();
        }
        if (tid == 0) bsum2[blk] = s[0];
    }
    grid.sync();
    if (blk == 0) {  // step B: scan block sums (NB2 <= 1024)
        int v = (tid < NB2) ? bsum2[tid] : 0;
        s[tid] = v;
        __syncthreads();
        for (int off = 1; off < CTHR; off <<= 1) {
            int u = (tid >= off) ? s[tid - off] : 0;
            __syncthreads();
            s[tid] += u;
            __syncthreads();
        }
        if (tid < NB2) boff2[tid] = s[tid] - v;
    }
    grid.sync();
    if (blk < NB2) {  // step C: final exclusive scan
        int i = blk * CTHR + tid;
        int v = (i < clen) ? cnt[i] : 0;
        s[tid] = v;
        __syncthreads();
        for (int off = 1; off < CTHR; off <<= 1) {
            int u = (tid >= off) ? s[tid - off] : 0;
            __syncthreads();
            s[tid] += u;
            __syncthreads();
        }
        if (i < clen) cbase[i] = boff2[blk] + s[tid] - v;
    }
    grid.sync();
    // ---- phase2: dense packed pair write ----
    for (int b = tid; b < nbuk; b += CTHR) h[b] = cbase[b * NBLK + blk];
    __syncthreads();
#pragma unroll
    for (int k = 0; k < MAXK; ++k) {
        if (ps[k] >= 0) {
            int slot = atomicAdd(&h[ps[k] >> BKT_SHIFT], 1);
            pairs[slot] = (unsigned)sr[k] | ((unsigned)(ps[k] & (BKT - 1)) << 17);
        }
    }
}

// ---------------- bucket-local LDS-staged final scatter: dense 64B writes ----------------
__global__ __launch_bounds__(1024) void k_scat2(const unsigned int* __restrict__ pairs, int E,
                                                int* __restrict__ csr) {
    __shared__ int buf[BKT];  // 16 KB
    int b = blockIdx.x;
    int base = b << BKT_SHIFT;
    int n = min(BKT, E - base);
    for (int i = threadIdx.x; i < n; i += 1024) {
        unsigned int p = pairs[base + i];
        buf[p >> 17] = (int)(p & 0x1FFFFu);
    }
    __syncthreads();
    int n4 = n >> 2;
    for (int i = threadIdx.x; i < n4; i += 1024)
        ((int4*)(csr + base))[i] = ((const int4*)buf)[i];
    for (int i = (n4 << 2) + threadIdx.x; i < n; i += 1024)
        csr[base + i] = buf[i];
}

// ---------------- cast + pre-scale x: xh[i] = half(x[i] * dinv[node]) ----------------
__global__ __launch_bounds__(256) void k_cast32(const float* __restrict__ x, const float* __restrict__ dinv,
                                                __half* __restrict__ xh, int N) {
    int i = blockIdx.x * 256 + threadIdx.x;  // group of 4 elems
    if (i >= N * 8) return;
    int g = i >> 3;
    float di = dinv[g];
    float4 v = ((const float4*)x)[i];
    __half2 h0 = __floats2half2_rn(v.x * di, v.y * di);
    __half2 h1 = __floats2half2_rn(v.z * di, v.w * di);
    ((__half2*)xh)[2 * i] = h0;
    ((__half2*)xh)[2 * i + 1] = h1;
}

// ---------------- aggregation: 8 features per lane (16 B gathers) ----------------
template <int F>
__global__ __launch_bounds__(256) void k_agg(const __half* __restrict__ feat,
                                             const int* __restrict__ offsets,
                                             const int* __restrict__ csr_src,
                                             const float* __restrict__ dinv,
                                             float* __restrict__ out, int N) {
    constexpr int L = F / 8;  // lanes per node
    int t = blockIdx.x * 256 + threadIdx.x;
    int g = t / L;
    int q = t % L;            // feature octet index
    if (g >= N) return;
    const h2x4* f8 = (const h2x4*)feat;
    int beg = offsets[g];
    int end = offsets[g + 1];
    float di = dinv[g];
    float acc[8];
    {
        h2x4 w = f8[(size_t)g * L + q];
        float2 p0 = __half22float2(w.a), p1 = __half22float2(w.b);
        float2 p2 = __half22float2(w.c), p3 = __half22float2(w.d);
        acc[0] = p0.x; acc[1] = p0.y; acc[2] = p1.x; acc[3] = p1.y;
        acc[4] = p2.x; acc[5] = p2.y; acc[6] = p3.x; acc[7] = p3.y;
    }
    int e = beg;
    for (; e + 4 <= end; e += 4) {
        int s0 = csr_src[e + 0], s1 = csr_src[e + 1], s2 = csr_src[e + 2], s3 = csr_src[e + 3];
        h2x4 w0 = f8[(size_t)s0 * L + q];
        h2x4 w1 = f8[(size_t)s1 * L + q];
        h2x4 w2 = f8[(size_t)s2 * L + q];
        h2x4 w3 = f8[(size_t)s3 * L + q];
        float2 u;
        u = __half22float2(w0.a); acc[0] += u.x; acc[1] += u.y;
        u = __half22float2(w0.b); acc[2] += u.x; acc[3] += u.y;
        u = __half22float2(w0.c); acc[4] += u.x; acc[5] += u.y;
        u = __half22float2(w0.d); acc[6] += u.x; acc[7] += u.y;
        u = __half22float2(w1.a); acc[0] += u.x; acc[1] += u.y;
        u = __half22float2(w1.b); acc[2] += u.x; acc[3] += u.y;
        u = __half22float2(w1.c); acc[4] += u.x; acc[5] += u.y;
        u = __half22float2(w1.d); acc[6] += u.x; acc[7] += u.y;
        u = __half22float2(w2.a); acc[0] += u.x; acc[1] += u.y;
        u = __half22float2(w2.b); acc[2] += u.x; acc[3] += u.y;
        u = __half22float2(w2.c); acc[4] += u.x; acc[5] += u.y;
        u = __half22float2(w2.d); acc[6] += u.x; acc[7] += u.y;
        u = __half22float2(w3.a); acc[0] += u.x; acc[1] += u.y;
        u = __half22float2(w3.b); acc[2] += u.x; acc[3] += u.y;
        u = __half22float2(w3.c); acc[4] += u.x; acc[5] += u.y;
        u = __half22float2(w3.d); acc[6] += u.x; acc[7] += u.y;
    }
    for (; e < end; ++e) {
        h2x4 w = f8[(size_t)csr_src[e] * L + q];
        float2 u;
        u = __half22float2(w.a); acc[0] += u.x; acc[1] += u.y;
        u = __half22float2(w.b); acc[2] += u.x; acc[3] += u.y;
        u = __half22float2(w.c); acc[4] += u.x; acc[5] += u.y;
        u = __half22float2(w.d); acc[6] += u.x; acc[7] += u.y;
    }
    float4 o0 = make_float4(acc[0] * di, acc[1] * di, acc[2] * di, acc[3] * di);
    float4 o1 = make_float4(acc[4] * di, acc[5] * di, acc[6] * di, acc[7] * di);
    ((float4*)out)[(size_t)g * (F / 4) + q * 2] = o0;
    ((float4*)out)[(size_t)g * (F / 4) + q * 2 + 1] = o1;
}

// ---------------- GEMM1: h2h = half( relu(A[Nx32] @ W1 + b1) * dinv[row] ) ----------------
__global__ __launch_bounds__(256) void k_gemm1(const float* __restrict__ A, const float* __restrict__ W,
                                               const float* __restrict__ b, const float* __restrict__ dinv,
                                               __half* __restrict__ out, int N) {
    __shared__ float sA[32][68];
    __shared__ float sW[32][64];
    int tid = threadIdx.x;
    int row0 = blockIdx.x * 64;

    {
        const float4* Wv = (const float4*)W;
        float4* sWv = (float4*)&sW[0][0];
        sWv[tid] = Wv[tid];
        sWv[tid + 256] = Wv[tid + 256];
    }
    {
        int row = tid >> 2;
        int gr = row0 + row;
        int kq = (tid & 3) * 4;
#pragma unroll
        for (int i = 0; i < 2; ++i) {
            int k0 = kq + 16 * i;
            float4 v = (gr < N) ? *(const float4*)(A + (size_t)gr * 32 + k0)
                                : make_float4(0.f, 0.f, 0.f, 0.f);
            sA[k0 + 0][row] = v.x;
            sA[k0 + 1][row] = v.y;
            sA[k0 + 2][row] = v.z;
            sA[k0 + 3][row] = v.w;
        }
    }
    __syncthreads();

    int tm = tid & 15, tn = tid >> 4;
    float acc[4][4];
#pragma unroll
    for (int i = 0; i < 4; ++i) {
        float4 bb = *(const float4*)(b + tn * 4);
        acc[i][0] = bb.x; acc[i][1] = bb.y; acc[i][2] = bb.z; acc[i][3] = bb.w;
    }
#pragma unroll 4
    for (int k = 0; k < 32; ++k) {
        float4 a = *(const float4*)&sA[k][tm * 4];
        float4 w = *(const float4*)&sW[k][tn * 4];
        float av[4] = {a.x, a.y, a.z, a.w};
        float wv[4] = {w.x, w.y, w.z, w.w};
#pragma unroll
        for (int i = 0; i < 4; ++i)
#pragma unroll
            for (int j = 0; j < 4; ++j) acc[i][j] = fmaf(av[i], wv[j], acc[i][j]);
    }
#pragma unroll
    for (int i = 0; i < 4; ++i) {
        int row = row0 + tm * 4 + i;
        if (row < N) {
            float di = dinv[row];
            __half2 p0 = __floats2half2_rn(fmaxf(acc[i][0], 0.f) * di, fmaxf(acc[i][1], 0.f) * di);
            __half2 p1 = __floats2half2_rn(fmaxf(acc[i][2], 0.f) * di, fmaxf(acc[i][3], 0.f) * di);
            __half2* op = (__half2*)(out + (size_t)row * 64);
            op[tn * 2] = p0;
            op[tn * 2 + 1] = p1;
        }
    }
}

// ---------------- GEMM2: out = A[Nx64] @ W2[64x128] + b2 ----------------
__global__ __launch_bounds__(256) void k_gemm2(const float* __restrict__ A, const float* __restrict__ W,
                                               const float* __restrict__ b, float* __restrict__ out, int N) {
    __shared__ float sA[64][68];
    __shared__ float sW[64][128];
    int tid = threadIdx.x;
    int row0 = blockIdx.x * 64;

    {
        const float4* Wv = (const float4*)W;
        float4* sWv = (float4*)&sW[0][0];
#pragma unroll
        for (int i = 0; i < 8; ++i) sWv[tid + 256 * i] = Wv[tid + 256 * i];
    }
    {
        int row = tid >> 2;
        int gr = row0 + row;
        int kq = (tid & 3) * 4;
#pragma unroll
        for (int i = 0; i < 4; ++i) {
            int k0 = kq + 16 * i;
            float4 v = (gr < N) ? *(const float4*)(A + (size_t)gr * 64 + k0)
                                : make_float4(0.f, 0.f, 0.f, 0.f);
            sA[k0 + 0][row] = v.x;
            sA[k0 + 1][row] = v.y;
            sA[k0 + 2][row] = v.z;
            sA[k0 + 3][row] = v.w;
        }
    }
    __syncthreads();

    int tm = tid & 15, tn = tid >> 4;
    float acc[4][8];
    {
        float4 b0 = *(const float4*)(b + tn * 8);
        float4 b1 = *(const float4*)(b + tn * 8 + 4);
#pragma unroll
        for (int i = 0; i < 4; ++i) {
            acc[i][0] = b0.x; acc[i][1] = b0.y; acc[i][2] = b0.z; acc[i][3] = b0.w;
            acc[i][4] = b1.x; acc[i][5] = b1.y; acc[i][6] = b1.z; acc[i][7] = b1.w;
        }
    }
#pragma unroll 4
    for (int k = 0; k < 64; ++k) {
        float4 a = *(const float4*)&sA[k][tm * 4];
        float4 w0 = *(const float4*)&sW[k][tn * 8];
        float4 w1 = *(const float4*)&sW[k][tn * 8 + 4];
        float av[4] = {a.x, a.y, a.z, a.w};
        float wv[8] = {w0.x, w0.y, w0.z, w0.w, w1.x, w1.y, w1.z, w1.w};
#pragma unroll
        for (int i = 0; i < 4; ++i)
#pragma unroll
            for (int j = 0; j < 8; ++j) acc[i][j] = fmaf(av[i], wv[j], acc[i][j]);
    }
#pragma unroll
    for (int i = 0; i < 4; ++i) {
        int row = row0 + tm * 4 + i;
        if (row < N) {
            *(float4*)(out + (size_t)row * 128 + tn * 8) =
                make_float4(acc[i][0], acc[i][1], acc[i][2], acc[i][3]);
            *(float4*)(out + (size_t)row * 128 + tn * 8 + 4) =
                make_float4(acc[i][4], acc[i][5], acc[i][6], acc[i][7]);
        }
    }
}

extern "C" void kernel_launch(void* const* d_in, const int* in_sizes, int n_in,
                              void* d_out, int out_size, void* d_ws, size_t ws_size,
                              hipStream_t stream) {
    const float* x  = (const float*)d_in[0];
    const int*   ei = (const int*)d_in[1];
    const float* W1 = (const float*)d_in[2];
    const float* b1 = (const float*)d_in[3];
    const float* W2 = (const float*)d_in[4];
    const float* b2 = (const float*)d_in[5];
    float* out = (float*)d_out;

    const int N = in_sizes[0] / 32;
    const int E = in_sizes[1] / 2;
    const int chunk = cdiv(E, HC);
    const int epb = cdiv(E, NBLK);
    const int nbuk = cdiv(E, BKT);         // 391 for E=1.6M (<=512)
    const int clen = nbuk * NBLK;

    char* ws = (char*)d_ws;
    size_t off = 0;
    auto walloc = [&](size_t bytes) -> void* {
        void* p = ws + off;
        off = (off + bytes + 255) & ~(size_t)255;
        return p;
    };
    unsigned char* Mb      = (unsigned char*) walloc((size_t)HC * N);        // 6.4 MB
    unsigned char* pre8    = (unsigned char*) walloc((size_t)HC * N);        // 6.4 MB
    int*           deg     = (int*)           walloc((size_t)N * 4);
    float*         dinv    = (float*)         walloc((size_t)N * 4);
    int*           offsets = (int*)           walloc((size_t)(N + 4) * 4);
    int*           bsum    = (int*)           walloc(128 * 4);
    int*           boff    = (int*)           walloc(128 * 4);
    unsigned char* rank8   = (unsigned char*) walloc((size_t)E);             // 1.6 MB
    int*           cnt     = (int*)           walloc((size_t)(clen + 4) * 4);
    int*           bsum2   = (int*)           walloc(1024 * 4);
    int*           boff2   = (int*)           walloc(1024 * 4);
    int*           cbase   = (int*)           walloc((size_t)(clen + 4) * 4);
    unsigned int*  pairs   = (unsigned int*)  walloc((size_t)E * 4);         // 6.4 MB
    int*           csr_src = (int*)           walloc((size_t)E * 4);         // 6.4 MB
    __half*        xh      = (__half*)        walloc((size_t)N * 32 * 2);    // 6.4 MB
    float*         a1      = (float*)         walloc((size_t)N * 32 * 4);    // 12.8 MB
    __half*        h2h     = (__half*)        walloc((size_t)N * 64 * 2);    // 12.8 MB
    float*         a2      = (float*)         walloc((size_t)N * 64 * 4);    // 25.6 MB
    (void)ws_size; (void)n_in; (void)out_size;

    k_hist<<<HC, 1024, 0, stream>>>(ei + E, E, N, chunk, rank8, Mb);
    k_degpre<<<cdiv(N / 4, 256), 256, 0, stream>>>(Mb, N, pre8, deg, dinv);

    const int NB = cdiv(N, SCAN_BS);
    k_blocksum<<<NB, SCAN_BS, 0, stream>>>(deg, N, bsum);
    k_scan_bsums<<<1, 128, 0, stream>>>(bsum, NB, boff);
    k_scan_final<<<NB, SCAN_BS, 0, stream>>>(deg, N, boff, offsets, E);

    k_cast32<<<cdiv(N * 8, 256), 256, 0, stream>>>(x, dinv, xh, N);

    {
        const int* ei_ = ei; int E_ = E, N_ = N, chunk_ = chunk, epb_ = epb, nbuk_ = nbuk, clen_ = clen;
        const int* offsets_ = offsets;
        const unsigned char* pre8_ = pre8;
        const unsigned char* rank8_ = rank8;
        int* cnt_ = cnt; int* bsum2_ = bsum2; int* boff2_ = boff2; int* cbase_ = cbase;
        unsigned int* pairs_ = pairs;
        void* args[] = {&ei_, &E_, &N_, &chunk_, &epb_, &nbuk_, &clen_,
                        &offsets_, &pre8_, &rank8_, &cnt_, &bsum2_, &boff2_, &cbase_, &pairs_};
        hipLaunchCooperativeKernel((const void*)k_sortcsr, dim3(NBLK), dim3(CTHR), args, 0, stream);
    }
    k_scat2<<<nbuk, 1024, 0, stream>>>(pairs, E, csr_src);

    k_agg<32><<<cdiv(N * 4, 256), 256, 0, stream>>>(xh, offsets, csr_src, dinv, a1, N);
    k_gemm1<<<cdiv(N, 64), 256, 0, stream>>>(a1, W1, b1, dinv, h2h, N);

    k_agg<64><<<cdiv(N * 8, 256), 256, 0, stream>>>(h2h, offsets, csr_src, dinv, a2, N);
    k_gemm2<<<cdiv(N, 64), 256, 0, stream>>>(a2, W2, b2, out, N);
}